// Round 10
// baseline (422.022 us; speedup 1.0000x reference)
//
#include <hip/hip_runtime.h>

#define B 8
#define C 512
#define H 96
#define W 96
#define HW (H*W)       // 9216
#define KD 512
#define NSP 9216

typedef __attribute__((ext_vector_type(4))) float f32x4;
typedef __attribute__((ext_vector_type(8))) _Float16 f16x8;

// global -> LDS async copy, 16B per lane.
typedef __attribute__((address_space(3))) unsigned int lds_u32;
typedef const __attribute__((address_space(1))) unsigned int glb_u32;
static __device__ __forceinline__ void gload16(const void* gsrc, void* ldst) {
    __builtin_amdgcn_global_load_lds((glb_u32*)gsrc, (lds_u32*)ldst, 16, 0, 0);
}

// swizzle for [rows][32-elem] tiles (64B rows, 4 granules of 8) — agg satt only
static __device__ __forceinline__ int tidx(int row, int kgrp) {
    return row * 32 + ((kgrp ^ ((row >> 2) & 3)) << 3);
}
// swizzle for [rows][64-elem] tiles (128B rows, 8 granules) — energy kernel
static __device__ __forceinline__ int tidx64(int row, int gr) {
    return row * 64 + ((gr ^ (row & 7)) << 3);
}

// ---------------------------------------------------------------------------
// Split weights to fp16: Wv single; Wqk = [Wq;Wk] hi/lo pairs.
// ---------------------------------------------------------------------------
__global__ __launch_bounds__(256) void split_w(
    const float* __restrict__ Wv, const float* __restrict__ Wq, const float* __restrict__ Wk,
    _Float16* __restrict__ Wv_h,
    _Float16* __restrict__ Wqk_h, _Float16* __restrict__ Wqk_l)
{
    int i = blockIdx.x * 256 + threadIdx.x;
    if (i < C * C) Wv_h[i] = (_Float16)Wv[i];
    if (i < 128 * C) {
        int m = i / C, k = i % C;
        float f = (m < 64) ? Wq[m * C + k] : Wk[(m - 64) * C + k];
        _Float16 h = (_Float16)f;
        Wqk_h[i] = h;
        Wqk_l[i] = (_Float16)(f - (float)h);
    }
}

// ---------------------------------------------------------------------------
// Global transpose+split of x: (B,K,N) fp32 -> xhT/xlT (B,N,K) fp16.
// v3: two 64x64 k-tiles per block (8 loads in flight), nontemporal streams.
// ---------------------------------------------------------------------------
__global__ __launch_bounds__(256) void split_x(
    const float* __restrict__ x,
    _Float16* __restrict__ xhT, _Float16* __restrict__ xlT)
{
    __shared__ float t[2][64][65];      // 33.3 KB
    int n0 = blockIdx.x * 64, k0 = blockIdx.y * 128, b = blockIdx.z;
    int tid = threadIdx.x;
    const float* xb = x + ((size_t)b * KD + k0) * NSP + n0;

    // load both tiles: 8 x float4 per thread, all issued before any LDS use
    f32x4 v[8];
    #pragma unroll
    for (int it = 0; it < 8; ++it) {
        int idx = tid + it * 256;               // 0..2047
        int tile = idx >> 10, kr = (idx >> 4) & 63, nq = idx & 15;
        v[it] = __builtin_nontemporal_load(
            (const f32x4*)&xb[(size_t)(tile * 64 + kr) * NSP + nq * 4]);
    }
    #pragma unroll
    for (int it = 0; it < 8; ++it) {
        int idx = tid + it * 256;
        int tile = idx >> 10, kr = (idx >> 4) & 63, nq = idx & 15;
        #pragma unroll
        for (int u = 0; u < 4; ++u) t[tile][kr][nq * 4 + u] = v[it][u];
    }
    __syncthreads();
    #pragma unroll
    for (int it = 0; it < 4; ++it) {
        int gid = tid + it * 256;               // 0..1023
        int tile = gid >> 9, w2 = gid & 511;
        int n = w2 >> 3, g = w2 & 7;
        f16x8 hi, lo;
        #pragma unroll
        for (int u = 0; u < 8; ++u) {
            float f = t[tile][g * 8 + u][n];
            _Float16 hh = (_Float16)f;
            hi[u] = hh;
            lo[u] = (_Float16)(f - (float)hh);
        }
        size_t off = ((size_t)b * NSP + n0 + n) * KD + k0 + tile * 64 + g * 8;
        __builtin_nontemporal_store(hi, (f16x8*)&xhT[off]);
        __builtin_nontemporal_store(lo, (f16x8*)&xlT[off]);
    }
}

// ---------------------------------------------------------------------------
// v projection: single-pass fp16 MFMA GEMM (fp32 accum), gload_lds staging.
// ---------------------------------------------------------------------------
__global__ __launch_bounds__(256, 2) void gemm_v(
    const _Float16* __restrict__ xhT,
    const _Float16* __restrict__ Wh,
    const float* __restrict__ bias,
    _Float16* __restrict__ out16)
{
    __shared__ _Float16 smem[8192];     // [W 128x32 | X 128x32] = 16 KB, linear
    const int W_OFF = 0, X_OFF = 4096;

    int tid = threadIdx.x;
    int n0 = blockIdx.x * 128, m0 = blockIdx.y * 128, b = blockIdx.z;
    int lane = tid & 63, wave = tid >> 6;
    int wr = wave >> 1, wc = wave & 1;
    int l15 = lane & 15, l4 = lane >> 4;

    int grow = tid >> 2, gcol = (tid & 3) * 8;
    const _Float16* pW = Wh + (size_t)(m0 + grow) * KD + gcol;
    const _Float16* pX = xhT + ((size_t)b * NSP + n0 + grow) * KD + gcol;
    const size_t half = (size_t)64 * KD;
    int ldsW0 = W_OFF + wave * 512;
    int ldsW1 = W_OFF + 2048 + wave * 512;
    int ldsX0 = X_OFF + wave * 512;
    int ldsX1 = X_OFF + 2048 + wave * 512;

    f32x4 acc[4][4];
    #pragma unroll
    for (int i = 0; i < 4; ++i)
        #pragma unroll
        for (int j = 0; j < 4; ++j)
            acc[i][j] = (f32x4){0.f, 0.f, 0.f, 0.f};

    for (int k0 = 0; k0 < KD; k0 += 32) {
        gload16(pW + k0,        &smem[ldsW0]);
        gload16(pW + half + k0, &smem[ldsW1]);
        gload16(pX + k0,        &smem[ldsX0]);
        gload16(pX + half + k0, &smem[ldsX1]);
        __syncthreads();

        f16x8 af[4], bf[4];
        #pragma unroll
        for (int f = 0; f < 4; ++f) {
            af[f] = *(const f16x8*)&smem[W_OFF + (wr * 64 + f * 16 + l15) * 32 + l4 * 8];
            bf[f] = *(const f16x8*)&smem[X_OFF + (wc * 64 + f * 16 + l15) * 32 + l4 * 8];
        }
        #pragma unroll
        for (int i = 0; i < 4; ++i)
            #pragma unroll
            for (int j = 0; j < 4; ++j)
                acc[i][j] = __builtin_amdgcn_mfma_f32_16x16x32_f16(af[i], bf[j], acc[i][j], 0, 0, 0);
        __syncthreads();
    }

    #pragma unroll
    for (int i = 0; i < 4; ++i)
        #pragma unroll
        for (int r = 0; r < 4; ++r) {
            int row = m0 + wr * 64 + i * 16 + l4 * 4 + r;
            float bv = bias[row];
            #pragma unroll
            for (int j = 0; j < 4; ++j) {
                int col = n0 + wc * 64 + j * 16 + l15;
                __builtin_nontemporal_store((_Float16)(acc[i][j][r] + bv),
                    &out16[((size_t)b * C + row) * NSP + col]);
            }
        }
}

// ---------------------------------------------------------------------------
// q/k projection: 3-pass fp16 (Ah*Bh + Ah*Bl + Al*Bh).
// ---------------------------------------------------------------------------
__global__ __launch_bounds__(256, 2) void gemm_qk(
    const _Float16* __restrict__ xhT, const _Float16* __restrict__ xlT,
    const _Float16* __restrict__ Wqh, const _Float16* __restrict__ Wql,
    const float* __restrict__ bias0, const float* __restrict__ bias1,
    _Float16* __restrict__ qh, _Float16* __restrict__ ql,
    _Float16* __restrict__ kh, _Float16* __restrict__ kl)
{
    __shared__ _Float16 smem[16384];    // [XH|XL|WH|WL] each 128x32 = 32 KB
    const int XH = 0, XL = 4096, WHo = 8192, WLo = 12288;

    int tid = threadIdx.x;
    int n0 = blockIdx.x * 128, b = blockIdx.z;
    int lane = tid & 63, wave = tid >> 6;
    int wr = wave >> 1, wc = wave & 1;
    int l15 = lane & 15, l4 = lane >> 4;

    int grow = tid >> 2, gcol = (tid & 3) * 8;
    const _Float16* pXh = xhT + ((size_t)b * NSP + n0 + grow) * KD + gcol;
    const _Float16* pXl = xlT + ((size_t)b * NSP + n0 + grow) * KD + gcol;
    const _Float16* pWh = Wqh + (size_t)grow * KD + gcol;
    const _Float16* pWl = Wql + (size_t)grow * KD + gcol;
    const size_t half = (size_t)64 * KD;
    int base0 = wave * 512, base1 = 2048 + wave * 512;

    f32x4 acc[4][4];
    #pragma unroll
    for (int i = 0; i < 4; ++i)
        #pragma unroll
        for (int j = 0; j < 4; ++j)
            acc[i][j] = (f32x4){0.f, 0.f, 0.f, 0.f};

    for (int k0 = 0; k0 < KD; k0 += 32) {
        gload16(pXh + k0,        &smem[XH + base0]);
        gload16(pXh + half + k0, &smem[XH + base1]);
        gload16(pXl + k0,        &smem[XL + base0]);
        gload16(pXl + half + k0, &smem[XL + base1]);
        gload16(pWh + k0,        &smem[WHo + base0]);
        gload16(pWh + half + k0, &smem[WHo + base1]);
        gload16(pWl + k0,        &smem[WLo + base0]);
        gload16(pWl + half + k0, &smem[WLo + base1]);
        __syncthreads();

        f16x8 axh[4], axl[4], bwh[4], bwl[4];
        #pragma unroll
        for (int f = 0; f < 4; ++f) {
            int ra = (wr * 64 + f * 16 + l15) * 32 + l4 * 8;
            int rb = (wc * 64 + f * 16 + l15) * 32 + l4 * 8;
            axh[f] = *(const f16x8*)&smem[XH + ra];
            axl[f] = *(const f16x8*)&smem[XL + ra];
            bwh[f] = *(const f16x8*)&smem[WHo + rb];
            bwl[f] = *(const f16x8*)&smem[WLo + rb];
        }
        #pragma unroll
        for (int i = 0; i < 4; ++i)
            #pragma unroll
            for (int j = 0; j < 4; ++j)
                acc[i][j] = __builtin_amdgcn_mfma_f32_16x16x32_f16(axh[i], bwh[j], acc[i][j], 0, 0, 0);
        #pragma unroll
        for (int i = 0; i < 4; ++i)
            #pragma unroll
            for (int j = 0; j < 4; ++j)
                acc[i][j] = __builtin_amdgcn_mfma_f32_16x16x32_f16(axh[i], bwl[j], acc[i][j], 0, 0, 0);
        #pragma unroll
        for (int i = 0; i < 4; ++i)
            #pragma unroll
            for (int j = 0; j < 4; ++j)
                acc[i][j] = __builtin_amdgcn_mfma_f32_16x16x32_f16(axl[i], bwh[j], acc[i][j], 0, 0, 0);
        __syncthreads();
    }

    #pragma unroll
    for (int i = 0; i < 4; ++i)
        #pragma unroll
        for (int r = 0; r < 4; ++r) {
            int sp = n0 + wr * 64 + i * 16 + l4 * 4 + r;
            #pragma unroll
            for (int j = 0; j < 4; ++j) {
                int wcol = wc * 64 + j * 16 + l15;
                float val = acc[i][j][r] + (wcol < 64 ? bias0[wcol] : bias1[wcol - 64]);
                _Float16 hi = (_Float16)val;
                _Float16 lo = (_Float16)(val - (float)hi);
                size_t off = ((size_t)b * NSP + sp) * 64 + (wcol & 63);
                if (wcol < 64) { qh[off] = hi; ql[off] = lo; }
                else           { kh[off] = hi; kl[off] = lo; }
            }
        }
}

// ---------------------------------------------------------------------------
// Energy MFMA: 3-pass fp16 + fused per-row (max, sum-exp) stats.
// Writes E-hat = E - rowmax(direction) as FP16 (halves E traffic).
// ---------------------------------------------------------------------------
__global__ __launch_bounds__(256, 2) void energy_mfma(
    const _Float16* __restrict__ qh, const _Float16* __restrict__ ql,
    const _Float16* __restrict__ kh, const _Float16* __restrict__ kl,
    _Float16* __restrict__ out16, float* __restrict__ part, int pMul, int rMul)
{
    __shared__ _Float16 sm[4 * 96 * 64];   // 48 KB
    const int T_QH = 0, T_QL = 6144, T_KH = 12288, T_KL = 18432;
    int p = blockIdx.x, b = blockIdx.y;
    int tid = threadIdx.x;
    size_t base = ((size_t)b * HW + (size_t)p * pMul) * 64;
    size_t rstride = (size_t)rMul * 64;

    #pragma unroll
    for (int tile = 0; tile < 4; ++tile) {
        const _Float16* src = (tile == 0) ? qh : (tile == 1) ? ql : (tile == 2) ? kh : kl;
        int tb = tile * 6144;
        #pragma unroll
        for (int sub = 0; sub < 3; ++sub) {
            int s = sub * 256 + tid;
            int row = s >> 3, g = s & 7;
            f16x8 d = *(const f16x8*)&src[base + row * rstride + g * 8];
            *(f16x8*)&sm[tb + tidx64(row, g)] = d;
        }
    }
    __syncthreads();

    int lane = tid & 63, wave = tid >> 6;
    int wr = wave >> 1, wc = wave & 1;
    int l15 = lane & 15, l4 = lane >> 4;

    f32x4 acc[3][3];
    #pragma unroll
    for (int i = 0; i < 3; ++i)
        #pragma unroll
        for (int j = 0; j < 3; ++j)
            acc[i][j] = (f32x4){0.f, 0.f, 0.f, 0.f};

    #pragma unroll
    for (int ks = 0; ks < 2; ++ks) {
        f16x8 Ah[3], Al[3], Bh[3], Bl[3];
        int gr = ks * 4 + l4;
        #pragma unroll
        for (int i = 0; i < 3; ++i) {
            int sa = tidx64(wr * 48 + i * 16 + l15, gr);
            Ah[i] = *(const f16x8*)&sm[T_QH + sa];
            Al[i] = *(const f16x8*)&sm[T_QL + sa];
            int sb = tidx64(wc * 48 + i * 16 + l15, gr);
            Bh[i] = *(const f16x8*)&sm[T_KH + sb];
            Bl[i] = *(const f16x8*)&sm[T_KL + sb];
        }
        #pragma unroll
        for (int i = 0; i < 3; ++i)
            #pragma unroll
            for (int j = 0; j < 3; ++j) {
                acc[i][j] = __builtin_amdgcn_mfma_f32_16x16x32_f16(Ah[i], Bh[j], acc[i][j], 0, 0, 0);
                acc[i][j] = __builtin_amdgcn_mfma_f32_16x16x32_f16(Ah[i], Bl[j], acc[i][j], 0, 0, 0);
                acc[i][j] = __builtin_amdgcn_mfma_f32_16x16x32_f16(Al[i], Bh[j], acc[i][j], 0, 0, 0);
            }
    }

    // ---- per-row stats (exact: block owns the full 96-col row) ----
    __syncthreads();                    // fragment ds_reads done -> reuse sm
    float* scr  = (float*)sm;           // [96][4]: mW0,s0,m1,s1
    float* scrM = scr + 384;            // [96]: full row max
    #pragma unroll
    for (int i = 0; i < 3; ++i)
        #pragma unroll
        for (int r = 0; r < 4; ++r) {
            int row = wr * 48 + i * 16 + l4 * 4 + r;
            float m3 = fmaxf(fmaxf(acc[i][0][r], acc[i][1][r]), acc[i][2][r]);
            #pragma unroll
            for (int mk = 1; mk < 16; mk <<= 1) m3 = fmaxf(m3, __shfl_xor(m3, mk));
            float s = __expf(acc[i][0][r] - m3) + __expf(acc[i][1][r] - m3) + __expf(acc[i][2][r] - m3);
            #pragma unroll
            for (int mk = 1; mk < 16; mk <<= 1) s += __shfl_xor(s, mk);
            if (l15 == 0) {
                scr[row * 4 + wc * 2]     = m3;
                scr[row * 4 + wc * 2 + 1] = s;
            }
        }
    __syncthreads();
    if (tid < 96) {
        float m0 = scr[tid * 4], s0 = scr[tid * 4 + 1];
        float m1 = scr[tid * 4 + 2], s1 = scr[tid * 4 + 3];
        float M = fmaxf(m0, m1);
        float S = s0 * __expf(m0 - M) + s1 * __expf(m1 - M);
        size_t idx = (pMul == 96) ? ((size_t)b * HW + p * 96 + tid)
                                  : ((size_t)b * HW + tid * 96 + p);
        part[idx * 2]     = M;
        part[idx * 2 + 1] = S;
        scrM[tid] = M;
    }
    __syncthreads();

    // ---- write E-hat = E - rowmax as fp16 ----
    size_t ob = (size_t)(b * 96 + p) * 9216;
    #pragma unroll
    for (int i = 0; i < 3; ++i)
        #pragma unroll
        for (int r = 0; r < 4; ++r) {
            int row = wr * 48 + i * 16 + l4 * 4 + r;
            float Mrow = scrM[row];
            #pragma unroll
            for (int j = 0; j < 3; ++j)
                __builtin_nontemporal_store((_Float16)(acc[i][j][r] - Mrow),
                    &out16[ob + (size_t)row * 96 + wc * 48 + j * 16 + l15]);
        }
}

// ---------------------------------------------------------------------------
// Combine W/H stats -> per-direction scales: msX = gamma*exp(mX-M)/S_total.
// P_joint = exp(Ehat_dir) * msDir  reproduces gamma * softmax exactly.
// ---------------------------------------------------------------------------
__global__ __launch_bounds__(256) void combine_ms(
    const float* __restrict__ pW, const float* __restrict__ pH,
    const float* __restrict__ gamma,
    float* __restrict__ msW, float* __restrict__ msH)
{
    int row = blockIdx.x * 256 + threadIdx.x;
    float mW = pW[row * 2], sW = pW[row * 2 + 1];
    float mH = pH[row * 2], sH = pH[row * 2 + 1];
    float M = fmaxf(mW, mH);
    float eW = __expf(mW - M), eH = __expf(mH - M);
    float g = gamma[0] / (sW * eW + sH * eH);
    msW[row] = g * eW;
    msH[row] = g * eH;
}

// ---------------------------------------------------------------------------
// MFMA aggregation: P staged once (from fp16 E-hat), v direct-from-global.
// ---------------------------------------------------------------------------
template<int OUT16>
__global__ __launch_bounds__(256) void agg_mfma(
    const _Float16* __restrict__ E16, const float* __restrict__ msDir,
    const _Float16* __restrict__ v16,
    float* __restrict__ dstF, _Float16* __restrict__ dstH, int msMode)
{
    __shared__ _Float16 satt[3][96 * 32];   // 18 KB

    int r = blockIdx.x, b = blockIdx.y;
    int tid = threadIdx.x;
    int lane = tid & 63, wave = tid >> 6;
    int l15 = lane & 15, l4 = lane >> 4;

    const _Float16* Eb = &E16[(size_t)(b * 96 + r) * 9216];
    int msBase = b * HW;
    #pragma unroll
    for (int it = 0; it < 5; ++it) {
        int g_id = tid + it * 256;
        if (g_id < 1152) {
            int s = g_id / 12, gj = g_id % 12;
            int mi = msMode ? (msBase + s * 96 + r) : (msBase + r * 96 + s);
            float sc = msDir[mi];
            f16x8 ev = *(const f16x8*)&Eb[s * 96 + gj * 8];
            f16x8 ph;
            #pragma unroll
            for (int u = 0; u < 8; ++u)
                ph[u] = (_Float16)(__expf((float)ev[u]) * sc);
            *(f16x8*)&satt[gj >> 2][tidx(s, gj & 3)] = ph;
        }
    }
    __syncthreads();

    const _Float16* vb = v16 + (size_t)b * C * 9216 + r * 96;

    for (int cc = 0; cc < 4; ++cc) {
        int cbase = cc * 128 + wave * 32;
        f32x4 acc[2][6];
        #pragma unroll
        for (int i = 0; i < 2; ++i)
            #pragma unroll
            for (int n = 0; n < 6; ++n)
                acc[i][n] = (f32x4){0.f, 0.f, 0.f, 0.f};

        #pragma unroll
        for (int kc = 0; kc < 3; ++kc) {
            f16x8 af[2];
            #pragma unroll
            for (int i = 0; i < 2; ++i)
                af[i] = *(const f16x8*)&vb[(size_t)(cbase + i * 16 + l15) * 9216 + kc * 32 + l4 * 8];
            f16x8 Bp[6];
            #pragma unroll
            for (int n = 0; n < 6; ++n)
                Bp[n] = *(const f16x8*)&satt[kc][tidx(n * 16 + l15, l4)];
            #pragma unroll
            for (int i = 0; i < 2; ++i)
                #pragma unroll
                for (int n = 0; n < 6; ++n)
                    acc[i][n] = __builtin_amdgcn_mfma_f32_16x16x32_f16(af[i], Bp[n], acc[i][n], 0, 0, 0);
        }

        #pragma unroll
        for (int i = 0; i < 2; ++i)
            #pragma unroll
            for (int r4 = 0; r4 < 4; ++r4) {
                int cl = cbase + i * 16 + l4 * 4 + r4;
                size_t rowb = ((size_t)b * C + cl) * 9216 + r * 96;
                #pragma unroll
                for (int n = 0; n < 6; ++n) {
                    int s = n * 16 + l15;
                    if (OUT16) __builtin_nontemporal_store((_Float16)acc[i][n][r4], &dstH[rowb + s]);
                    else       __builtin_nontemporal_store(acc[i][n][r4], &dstF[rowb + s]);
                }
            }
    }
}

// ---------------------------------------------------------------------------
// fp16 transpose, vectorized (f16x8 granules), nt streams.
// ---------------------------------------------------------------------------
__global__ __launch_bounds__(256) void transpose_f16(
    const _Float16* __restrict__ src, _Float16* __restrict__ dst)
{
    size_t base = (size_t)blockIdx.x * (96 * 96);
    __shared__ _Float16 t[96][104];
    int tid = threadIdx.x;
    for (int g = tid; g < 1152; g += 256) {
        int row = g / 12, c8 = (g % 12) * 8;
        f16x8 v = __builtin_nontemporal_load((const f16x8*)&src[base + row * 96 + c8]);
        *(f16x8*)&t[row][c8] = v;
    }
    __syncthreads();
    for (int g = tid; g < 1152; g += 256) {
        int row = g / 12, c8 = (g % 12) * 8;
        f16x8 o;
        #pragma unroll
        for (int u = 0; u < 8; ++u) o[u] = t[c8 + u][row];
        __builtin_nontemporal_store(o, (f16x8*)&dst[base + row * 96 + c8]);
    }
}

__global__ __launch_bounds__(256) void transpose_add(
    const _Float16* __restrict__ srcT, float* __restrict__ out)
{
    size_t base = (size_t)blockIdx.x * (96 * 96);
    __shared__ _Float16 t[96][104];
    int tid = threadIdx.x;
    for (int g = tid; g < 1152; g += 256) {
        int row = g / 12, c8 = (g % 12) * 8;
        f16x8 v = *(const f16x8*)&srcT[base + row * 96 + c8];
        *(f16x8*)&t[row][c8] = v;
    }
    __syncthreads();
    for (int i = tid; i < 96 * 96; i += 256) out[base + i] += (float)t[i % 96][i / 96];
}

// out = w16 + transpose(hT), vectorized, single fp32 write.
__global__ __launch_bounds__(256) void combine(
    const _Float16* __restrict__ w16, const _Float16* __restrict__ hT,
    float* __restrict__ out)
{
    size_t base = (size_t)blockIdx.x * (96 * 96);
    __shared__ _Float16 t[96][104];
    int tid = threadIdx.x;
    for (int g = tid; g < 1152; g += 256) {
        int row = g / 12, c8 = (g % 12) * 8;
        f16x8 v = __builtin_nontemporal_load((const f16x8*)&hT[base + row * 96 + c8]);
        *(f16x8*)&t[row][c8] = v;
    }
    __syncthreads();
    for (int g = tid; g < 1152; g += 256) {
        int row = g / 12, c8 = (g % 12) * 8;
        f16x8 wv = __builtin_nontemporal_load((const f16x8*)&w16[base + row * 96 + c8]);
        f32x4 o0, o1;
        #pragma unroll
        for (int u = 0; u < 4; ++u) o0[u] = (float)wv[u] + (float)t[c8 + u][row];
        #pragma unroll
        for (int u = 0; u < 4; ++u) o1[u] = (float)wv[4 + u] + (float)t[c8 + 4 + u][row];
        __builtin_nontemporal_store(o0, (f32x4*)&out[base + row * 96 + c8]);
        __builtin_nontemporal_store(o1, (f32x4*)&out[base + row * 96 + c8 + 4]);
    }
}

// ---------------------------------------------------------------------------
extern "C" void kernel_launch(void* const* d_in, const int* in_sizes, int n_in,
                              void* d_out, int out_size, void* d_ws, size_t ws_size,
                              hipStream_t stream)
{
    const float* x     = (const float*)d_in[0];
    const float* Wq    = (const float*)d_in[1];
    const float* bq    = (const float*)d_in[2];
    const float* Wk    = (const float*)d_in[3];
    const float* bk    = (const float*)d_in[4];
    const float* Wv    = (const float*)d_in[5];
    const float* bv    = (const float*)d_in[6];
    const float* gamma = (const float*)d_in[7];
    float* out = (float*)d_out;

    // Region plan (245.37 MB):
    // R1 75.5MB: xhT -> pW/pH (during energies) -> vB (after combine_ms)
    // R2 75.5MB: xlT -> vA (gemm_v out) -> outHT (after agg_W)
    // R3 37.7MB: q/k hi-lo -> msW/msH (after energies)
    // R4 28.3MB: W splits -> EH16
    // R5 28.3MB: EW16
    const size_t NK = (size_t)B * NSP * KD;
    _Float16* xhT = (_Float16*)d_ws;                         // R1
    _Float16* xlT = xhT + NK;                                // R2
    _Float16* qh  = xlT + NK;                                // R3
    _Float16* ql  = qh + (size_t)B * HW * 64;
    _Float16* kh  = ql + (size_t)B * HW * 64;
    _Float16* kl  = kh + (size_t)B * HW * 64;
    float* R4f = (float*)(kl + (size_t)B * HW * 64);         // R4 base
    float* R5f = R4f + (size_t)B * HW * 96;                  // R5 base
    _Float16* EH16 = (_Float16*)R4f;
    _Float16* EW16 = (_Float16*)R5f;
    float* msW = (float*)qh;                                 // R3 after energies
    float* msH = msW + (size_t)B * HW;
    _Float16* vA  = xlT;                                     // R2 after gemm_v
    _Float16* vB  = xhT;                                     // R1 after combine_ms
    _Float16* outHT = xlT;                                   // R2 after agg_W
    float* pW = (float*)xhT;                                 // R1 during energies
    float* pH = pW + (size_t)2 * B * HW;

    _Float16* Wv_h  = (_Float16*)R4f;                        // R4 until energies
    _Float16* Wqk_h = Wv_h + (size_t)C * C;
    _Float16* Wqk_l = Wqk_h + (size_t)128 * C;

    const size_t NEED = 245366784ull;
    bool bigws = ws_size >= NEED + NK * sizeof(_Float16);
    _Float16* outW16 = (_Float16*)((char*)d_ws + NEED);      // only if bigws

    dim3 blk(256);

    split_w<<<dim3((C*C + 255)/256), blk, 0, stream>>>(Wv, Wq, Wk, Wv_h, Wqk_h, Wqk_l);
    split_x<<<dim3(NSP/64, KD/128, B), blk, 0, stream>>>(x, xhT, xlT);

    // qk first (consumes xlT), then v (overwrites xlT slot with vA)
    gemm_qk<<<dim3(NSP/128, 1, B), blk, 0, stream>>>(xhT, xlT, Wqk_h, Wqk_l, bq, bk, qh, ql, kh, kl);
    gemm_v<<<dim3(NSP/128, C/128, B), blk, 0, stream>>>(xhT, Wv_h, bv, vA);

    // energies (fp16 E-hat) + fused row stats (partials land in dead R1)
    energy_mfma<<<dim3(96, B), blk, 0, stream>>>(qh, ql, kh, kl, EW16, pW, 96, 1);
    energy_mfma<<<dim3(96, B), blk, 0, stream>>>(qh, ql, kh, kl, EH16, pH, 1, 96);
    combine_ms<<<dim3(B*HW/256), blk, 0, stream>>>(pW, pH, gamma, msW, msH);

    // vB = transpose(vA) (overwrites R1 — partials consumed)
    transpose_f16<<<dim3(B*C), blk, 0, stream>>>(vA, vB);

    if (bigws) {
        agg_mfma<1><<<dim3(96, B), blk, 0, stream>>>(EW16, msW, vA, nullptr, outW16, 0);
        agg_mfma<1><<<dim3(96, B), blk, 0, stream>>>(EH16, msH, vB, nullptr, outHT, 1);
        combine<<<dim3(B*C), blk, 0, stream>>>(outW16, outHT, out);
    } else {
        agg_mfma<0><<<dim3(96, B), blk, 0, stream>>>(EW16, msW, vA, out, nullptr, 0);
        agg_mfma<1><<<dim3(96, B), blk, 0, stream>>>(EH16, msH, vB, nullptr, outHT, 1);
        transpose_add<<<dim3(B*C), blk, 0, stream>>>(outHT, out);
    }
}

// Round 11
// 356.032 us; speedup vs baseline: 1.1853x; 1.1853x over previous
//
#include <hip/hip_runtime.h>

#define B 8
#define C 512
#define H 96
#define W 96
#define HW (H*W)       // 9216
#define KD 512
#define NSP 9216

typedef __attribute__((ext_vector_type(4))) float f32x4;
typedef __attribute__((ext_vector_type(8))) _Float16 f16x8;

// global -> LDS async copy, 16B per lane.
typedef __attribute__((address_space(3))) unsigned int lds_u32;
typedef const __attribute__((address_space(1))) unsigned int glb_u32;
static __device__ __forceinline__ void gload16(const void* gsrc, void* ldst) {
    __builtin_amdgcn_global_load_lds((glb_u32*)gsrc, (lds_u32*)ldst, 16, 0, 0);
}

// swizzle for [rows][32-elem] tiles (64B rows, 4 granules of 8) — agg satt only
static __device__ __forceinline__ int tidx(int row, int kgrp) {
    return row * 32 + ((kgrp ^ ((row >> 2) & 3)) << 3);
}
// swizzle for [rows][64-elem] tiles (128B rows, 8 granules) — energy kernel
static __device__ __forceinline__ int tidx64(int row, int gr) {
    return row * 64 + ((gr ^ (row & 7)) << 3);
}

// ---------------------------------------------------------------------------
// Split weights to fp16: Wv single; Wqk = [Wq;Wk] hi/lo pairs.
// ---------------------------------------------------------------------------
__global__ __launch_bounds__(256) void split_w(
    const float* __restrict__ Wv, const float* __restrict__ Wq, const float* __restrict__ Wk,
    _Float16* __restrict__ Wv_h,
    _Float16* __restrict__ Wqk_h, _Float16* __restrict__ Wqk_l)
{
    int i = blockIdx.x * 256 + threadIdx.x;
    if (i < C * C) Wv_h[i] = (_Float16)Wv[i];
    if (i < 128 * C) {
        int m = i / C, k = i % C;
        float f = (m < 64) ? Wq[m * C + k] : Wk[(m - 64) * C + k];
        _Float16 h = (_Float16)f;
        Wqk_h[i] = h;
        Wqk_l[i] = (_Float16)(f - (float)h);
    }
}

// ---------------------------------------------------------------------------
// Global transpose+split of x: (B,K,N) fp32 -> xhT/xlT (B,N,K) fp16.
// Two 64x64 k-tiles per block (8 loads in flight). nt only on x loads
// (true read-once stream); REGULAR stores so consumers hit L2/L3.
// ---------------------------------------------------------------------------
__global__ __launch_bounds__(256) void split_x(
    const float* __restrict__ x,
    _Float16* __restrict__ xhT, _Float16* __restrict__ xlT)
{
    __shared__ float t[2][64][65];      // 33.3 KB
    int n0 = blockIdx.x * 64, k0 = blockIdx.y * 128, b = blockIdx.z;
    int tid = threadIdx.x;
    const float* xb = x + ((size_t)b * KD + k0) * NSP + n0;

    f32x4 v[8];
    #pragma unroll
    for (int it = 0; it < 8; ++it) {
        int idx = tid + it * 256;               // 0..2047
        int tile = idx >> 10, kr = (idx >> 4) & 63, nq = idx & 15;
        v[it] = __builtin_nontemporal_load(
            (const f32x4*)&xb[(size_t)(tile * 64 + kr) * NSP + nq * 4]);
    }
    #pragma unroll
    for (int it = 0; it < 8; ++it) {
        int idx = tid + it * 256;
        int tile = idx >> 10, kr = (idx >> 4) & 63, nq = idx & 15;
        #pragma unroll
        for (int u = 0; u < 4; ++u) t[tile][kr][nq * 4 + u] = v[it][u];
    }
    __syncthreads();
    #pragma unroll
    for (int it = 0; it < 4; ++it) {
        int gid = tid + it * 256;               // 0..1023
        int tile = gid >> 9, w2 = gid & 511;
        int n = w2 >> 3, g = w2 & 7;
        f16x8 hi, lo;
        #pragma unroll
        for (int u = 0; u < 8; ++u) {
            float f = t[tile][g * 8 + u][n];
            _Float16 hh = (_Float16)f;
            hi[u] = hh;
            lo[u] = (_Float16)(f - (float)hh);
        }
        size_t off = ((size_t)b * NSP + n0 + n) * KD + k0 + tile * 64 + g * 8;
        *(f16x8*)&xhT[off] = hi;
        *(f16x8*)&xlT[off] = lo;
    }
}

// ---------------------------------------------------------------------------
// v projection: single-pass fp16 MFMA GEMM (fp32 accum), gload_lds staging.
// ---------------------------------------------------------------------------
__global__ __launch_bounds__(256, 2) void gemm_v(
    const _Float16* __restrict__ xhT,
    const _Float16* __restrict__ Wh,
    const float* __restrict__ bias,
    _Float16* __restrict__ out16)
{
    __shared__ _Float16 smem[8192];     // [W 128x32 | X 128x32] = 16 KB, linear
    const int W_OFF = 0, X_OFF = 4096;

    int tid = threadIdx.x;
    int n0 = blockIdx.x * 128, m0 = blockIdx.y * 128, b = blockIdx.z;
    int lane = tid & 63, wave = tid >> 6;
    int wr = wave >> 1, wc = wave & 1;
    int l15 = lane & 15, l4 = lane >> 4;

    int grow = tid >> 2, gcol = (tid & 3) * 8;
    const _Float16* pW = Wh + (size_t)(m0 + grow) * KD + gcol;
    const _Float16* pX = xhT + ((size_t)b * NSP + n0 + grow) * KD + gcol;
    const size_t half = (size_t)64 * KD;
    int ldsW0 = W_OFF + wave * 512;
    int ldsW1 = W_OFF + 2048 + wave * 512;
    int ldsX0 = X_OFF + wave * 512;
    int ldsX1 = X_OFF + 2048 + wave * 512;

    f32x4 acc[4][4];
    #pragma unroll
    for (int i = 0; i < 4; ++i)
        #pragma unroll
        for (int j = 0; j < 4; ++j)
            acc[i][j] = (f32x4){0.f, 0.f, 0.f, 0.f};

    for (int k0 = 0; k0 < KD; k0 += 32) {
        gload16(pW + k0,        &smem[ldsW0]);
        gload16(pW + half + k0, &smem[ldsW1]);
        gload16(pX + k0,        &smem[ldsX0]);
        gload16(pX + half + k0, &smem[ldsX1]);
        __syncthreads();

        f16x8 af[4], bf[4];
        #pragma unroll
        for (int f = 0; f < 4; ++f) {
            af[f] = *(const f16x8*)&smem[W_OFF + (wr * 64 + f * 16 + l15) * 32 + l4 * 8];
            bf[f] = *(const f16x8*)&smem[X_OFF + (wc * 64 + f * 16 + l15) * 32 + l4 * 8];
        }
        #pragma unroll
        for (int i = 0; i < 4; ++i)
            #pragma unroll
            for (int j = 0; j < 4; ++j)
                acc[i][j] = __builtin_amdgcn_mfma_f32_16x16x32_f16(af[i], bf[j], acc[i][j], 0, 0, 0);
        __syncthreads();
    }

    #pragma unroll
    for (int i = 0; i < 4; ++i)
        #pragma unroll
        for (int r = 0; r < 4; ++r) {
            int row = m0 + wr * 64 + i * 16 + l4 * 4 + r;
            float bv = bias[row];
            #pragma unroll
            for (int j = 0; j < 4; ++j) {
                int col = n0 + wc * 64 + j * 16 + l15;
                out16[((size_t)b * C + row) * NSP + col] = (_Float16)(acc[i][j][r] + bv);
            }
        }
}

// ---------------------------------------------------------------------------
// q/k projection: 3-pass fp16 (Ah*Bh + Ah*Bl + Al*Bh).
// ---------------------------------------------------------------------------
__global__ __launch_bounds__(256, 2) void gemm_qk(
    const _Float16* __restrict__ xhT, const _Float16* __restrict__ xlT,
    const _Float16* __restrict__ Wqh, const _Float16* __restrict__ Wql,
    const float* __restrict__ bias0, const float* __restrict__ bias1,
    _Float16* __restrict__ qh, _Float16* __restrict__ ql,
    _Float16* __restrict__ kh, _Float16* __restrict__ kl)
{
    __shared__ _Float16 smem[16384];    // [XH|XL|WH|WL] each 128x32 = 32 KB
    const int XH = 0, XL = 4096, WHo = 8192, WLo = 12288;

    int tid = threadIdx.x;
    int n0 = blockIdx.x * 128, b = blockIdx.z;
    int lane = tid & 63, wave = tid >> 6;
    int wr = wave >> 1, wc = wave & 1;
    int l15 = lane & 15, l4 = lane >> 4;

    int grow = tid >> 2, gcol = (tid & 3) * 8;
    const _Float16* pXh = xhT + ((size_t)b * NSP + n0 + grow) * KD + gcol;
    const _Float16* pXl = xlT + ((size_t)b * NSP + n0 + grow) * KD + gcol;
    const _Float16* pWh = Wqh + (size_t)grow * KD + gcol;
    const _Float16* pWl = Wql + (size_t)grow * KD + gcol;
    const size_t half = (size_t)64 * KD;
    int base0 = wave * 512, base1 = 2048 + wave * 512;

    f32x4 acc[4][4];
    #pragma unroll
    for (int i = 0; i < 4; ++i)
        #pragma unroll
        for (int j = 0; j < 4; ++j)
            acc[i][j] = (f32x4){0.f, 0.f, 0.f, 0.f};

    for (int k0 = 0; k0 < KD; k0 += 32) {
        gload16(pXh + k0,        &smem[XH + base0]);
        gload16(pXh + half + k0, &smem[XH + base1]);
        gload16(pXl + k0,        &smem[XL + base0]);
        gload16(pXl + half + k0, &smem[XL + base1]);
        gload16(pWh + k0,        &smem[WHo + base0]);
        gload16(pWh + half + k0, &smem[WHo + base1]);
        gload16(pWl + k0,        &smem[WLo + base0]);
        gload16(pWl + half + k0, &smem[WLo + base1]);
        __syncthreads();

        f16x8 axh[4], axl[4], bwh[4], bwl[4];
        #pragma unroll
        for (int f = 0; f < 4; ++f) {
            int ra = (wr * 64 + f * 16 + l15) * 32 + l4 * 8;
            int rb = (wc * 64 + f * 16 + l15) * 32 + l4 * 8;
            axh[f] = *(const f16x8*)&smem[XH + ra];
            axl[f] = *(const f16x8*)&smem[XL + ra];
            bwh[f] = *(const f16x8*)&smem[WHo + rb];
            bwl[f] = *(const f16x8*)&smem[WLo + rb];
        }
        #pragma unroll
        for (int i = 0; i < 4; ++i)
            #pragma unroll
            for (int j = 0; j < 4; ++j)
                acc[i][j] = __builtin_amdgcn_mfma_f32_16x16x32_f16(axh[i], bwh[j], acc[i][j], 0, 0, 0);
        #pragma unroll
        for (int i = 0; i < 4; ++i)
            #pragma unroll
            for (int j = 0; j < 4; ++j)
                acc[i][j] = __builtin_amdgcn_mfma_f32_16x16x32_f16(axh[i], bwl[j], acc[i][j], 0, 0, 0);
        #pragma unroll
        for (int i = 0; i < 4; ++i)
            #pragma unroll
            for (int j = 0; j < 4; ++j)
                acc[i][j] = __builtin_amdgcn_mfma_f32_16x16x32_f16(axl[i], bwh[j], acc[i][j], 0, 0, 0);
        __syncthreads();
    }

    #pragma unroll
    for (int i = 0; i < 4; ++i)
        #pragma unroll
        for (int r = 0; r < 4; ++r) {
            int sp = n0 + wr * 64 + i * 16 + l4 * 4 + r;
            #pragma unroll
            for (int j = 0; j < 4; ++j) {
                int wcol = wc * 64 + j * 16 + l15;
                float val = acc[i][j][r] + (wcol < 64 ? bias0[wcol] : bias1[wcol - 64]);
                _Float16 hi = (_Float16)val;
                _Float16 lo = (_Float16)(val - (float)hi);
                size_t off = ((size_t)b * NSP + sp) * 64 + (wcol & 63);
                if (wcol < 64) { qh[off] = hi; ql[off] = lo; }
                else           { kh[off] = hi; kl[off] = lo; }
            }
        }
}

// ---------------------------------------------------------------------------
// Energy MFMA: 3-pass fp16 + fused per-row (max, sum-exp) stats.
// Writes E-hat = E - rowmax(direction) as FP16 (halves E traffic).
// ---------------------------------------------------------------------------
__global__ __launch_bounds__(256, 2) void energy_mfma(
    const _Float16* __restrict__ qh, const _Float16* __restrict__ ql,
    const _Float16* __restrict__ kh, const _Float16* __restrict__ kl,
    _Float16* __restrict__ out16, float* __restrict__ part, int pMul, int rMul)
{
    __shared__ _Float16 sm[4 * 96 * 64];   // 48 KB
    const int T_QH = 0, T_QL = 6144, T_KH = 12288, T_KL = 18432;
    int p = blockIdx.x, b = blockIdx.y;
    int tid = threadIdx.x;
    size_t base = ((size_t)b * HW + (size_t)p * pMul) * 64;
    size_t rstride = (size_t)rMul * 64;

    #pragma unroll
    for (int tile = 0; tile < 4; ++tile) {
        const _Float16* src = (tile == 0) ? qh : (tile == 1) ? ql : (tile == 2) ? kh : kl;
        int tb = tile * 6144;
        #pragma unroll
        for (int sub = 0; sub < 3; ++sub) {
            int s = sub * 256 + tid;
            int row = s >> 3, g = s & 7;
            f16x8 d = *(const f16x8*)&src[base + row * rstride + g * 8];
            *(f16x8*)&sm[tb + tidx64(row, g)] = d;
        }
    }
    __syncthreads();

    int lane = tid & 63, wave = tid >> 6;
    int wr = wave >> 1, wc = wave & 1;
    int l15 = lane & 15, l4 = lane >> 4;

    f32x4 acc[3][3];
    #pragma unroll
    for (int i = 0; i < 3; ++i)
        #pragma unroll
        for (int j = 0; j < 3; ++j)
            acc[i][j] = (f32x4){0.f, 0.f, 0.f, 0.f};

    #pragma unroll
    for (int ks = 0; ks < 2; ++ks) {
        f16x8 Ah[3], Al[3], Bh[3], Bl[3];
        int gr = ks * 4 + l4;
        #pragma unroll
        for (int i = 0; i < 3; ++i) {
            int sa = tidx64(wr * 48 + i * 16 + l15, gr);
            Ah[i] = *(const f16x8*)&sm[T_QH + sa];
            Al[i] = *(const f16x8*)&sm[T_QL + sa];
            int sb = tidx64(wc * 48 + i * 16 + l15, gr);
            Bh[i] = *(const f16x8*)&sm[T_KH + sb];
            Bl[i] = *(const f16x8*)&sm[T_KL + sb];
        }
        #pragma unroll
        for (int i = 0; i < 3; ++i)
            #pragma unroll
            for (int j = 0; j < 3; ++j) {
                acc[i][j] = __builtin_amdgcn_mfma_f32_16x16x32_f16(Ah[i], Bh[j], acc[i][j], 0, 0, 0);
                acc[i][j] = __builtin_amdgcn_mfma_f32_16x16x32_f16(Ah[i], Bl[j], acc[i][j], 0, 0, 0);
                acc[i][j] = __builtin_amdgcn_mfma_f32_16x16x32_f16(Al[i], Bh[j], acc[i][j], 0, 0, 0);
            }
    }

    // ---- per-row stats (exact: block owns the full 96-col row) ----
    __syncthreads();                    // fragment ds_reads done -> reuse sm
    float* scr  = (float*)sm;           // [96][4]: mW0,s0,m1,s1
    float* scrM = scr + 384;            // [96]: full row max
    #pragma unroll
    for (int i = 0; i < 3; ++i)
        #pragma unroll
        for (int r = 0; r < 4; ++r) {
            int row = wr * 48 + i * 16 + l4 * 4 + r;
            float m3 = fmaxf(fmaxf(acc[i][0][r], acc[i][1][r]), acc[i][2][r]);
            #pragma unroll
            for (int mk = 1; mk < 16; mk <<= 1) m3 = fmaxf(m3, __shfl_xor(m3, mk));
            float s = __expf(acc[i][0][r] - m3) + __expf(acc[i][1][r] - m3) + __expf(acc[i][2][r] - m3);
            #pragma unroll
            for (int mk = 1; mk < 16; mk <<= 1) s += __shfl_xor(s, mk);
            if (l15 == 0) {
                scr[row * 4 + wc * 2]     = m3;
                scr[row * 4 + wc * 2 + 1] = s;
            }
        }
    __syncthreads();
    if (tid < 96) {
        float m0 = scr[tid * 4], s0 = scr[tid * 4 + 1];
        float m1 = scr[tid * 4 + 2], s1 = scr[tid * 4 + 3];
        float M = fmaxf(m0, m1);
        float S = s0 * __expf(m0 - M) + s1 * __expf(m1 - M);
        size_t idx = (pMul == 96) ? ((size_t)b * HW + p * 96 + tid)
                                  : ((size_t)b * HW + tid * 96 + p);
        part[idx * 2]     = M;
        part[idx * 2 + 1] = S;
        scrM[tid] = M;
    }
    __syncthreads();

    // ---- write E-hat = E - rowmax as fp16 (regular stores: consumed by agg) ----
    size_t ob = (size_t)(b * 96 + p) * 9216;
    #pragma unroll
    for (int i = 0; i < 3; ++i)
        #pragma unroll
        for (int r = 0; r < 4; ++r) {
            int row = wr * 48 + i * 16 + l4 * 4 + r;
            float Mrow = scrM[row];
            #pragma unroll
            for (int j = 0; j < 3; ++j)
                out16[ob + (size_t)row * 96 + wc * 48 + j * 16 + l15] =
                    (_Float16)(acc[i][j][r] - Mrow);
        }
}

// ---------------------------------------------------------------------------
// Combine W/H stats -> per-direction scales: msX = gamma*exp(mX-M)/S_total.
// ---------------------------------------------------------------------------
__global__ __launch_bounds__(256) void combine_ms(
    const float* __restrict__ pW, const float* __restrict__ pH,
    const float* __restrict__ gamma,
    float* __restrict__ msW, float* __restrict__ msH)
{
    int row = blockIdx.x * 256 + threadIdx.x;
    float mW = pW[row * 2], sW = pW[row * 2 + 1];
    float mH = pH[row * 2], sH = pH[row * 2 + 1];
    float M = fmaxf(mW, mH);
    float eW = __expf(mW - M), eH = __expf(mH - M);
    float g = gamma[0] / (sW * eW + sH * eH);
    msW[row] = g * eW;
    msH[row] = g * eH;
}

// ---------------------------------------------------------------------------
// MFMA aggregation: P staged once (from fp16 E-hat), v direct-from-global.
// ---------------------------------------------------------------------------
template<int OUT16>
__global__ __launch_bounds__(256) void agg_mfma(
    const _Float16* __restrict__ E16, const float* __restrict__ msDir,
    const _Float16* __restrict__ v16,
    float* __restrict__ dstF, _Float16* __restrict__ dstH, int msMode)
{
    __shared__ _Float16 satt[3][96 * 32];   // 18 KB

    int r = blockIdx.x, b = blockIdx.y;
    int tid = threadIdx.x;
    int lane = tid & 63, wave = tid >> 6;
    int l15 = lane & 15, l4 = lane >> 4;

    const _Float16* Eb = &E16[(size_t)(b * 96 + r) * 9216];
    int msBase = b * HW;
    #pragma unroll
    for (int it = 0; it < 5; ++it) {
        int g_id = tid + it * 256;
        if (g_id < 1152) {
            int s = g_id / 12, gj = g_id % 12;
            int mi = msMode ? (msBase + s * 96 + r) : (msBase + r * 96 + s);
            float sc = msDir[mi];
            f16x8 ev = *(const f16x8*)&Eb[s * 96 + gj * 8];
            f16x8 ph;
            #pragma unroll
            for (int u = 0; u < 8; ++u)
                ph[u] = (_Float16)(__expf((float)ev[u]) * sc);
            *(f16x8*)&satt[gj >> 2][tidx(s, gj & 3)] = ph;
        }
    }
    __syncthreads();

    const _Float16* vb = v16 + (size_t)b * C * 9216 + r * 96;

    for (int cc = 0; cc < 4; ++cc) {
        int cbase = cc * 128 + wave * 32;
        f32x4 acc[2][6];
        #pragma unroll
        for (int i = 0; i < 2; ++i)
            #pragma unroll
            for (int n = 0; n < 6; ++n)
                acc[i][n] = (f32x4){0.f, 0.f, 0.f, 0.f};

        #pragma unroll
        for (int kc = 0; kc < 3; ++kc) {
            f16x8 af[2];
            #pragma unroll
            for (int i = 0; i < 2; ++i)
                af[i] = *(const f16x8*)&vb[(size_t)(cbase + i * 16 + l15) * 9216 + kc * 32 + l4 * 8];
            f16x8 Bp[6];
            #pragma unroll
            for (int n = 0; n < 6; ++n)
                Bp[n] = *(const f16x8*)&satt[kc][tidx(n * 16 + l15, l4)];
            #pragma unroll
            for (int i = 0; i < 2; ++i)
                #pragma unroll
                for (int n = 0; n < 6; ++n)
                    acc[i][n] = __builtin_amdgcn_mfma_f32_16x16x32_f16(af[i], Bp[n], acc[i][n], 0, 0, 0);
        }

        #pragma unroll
        for (int i = 0; i < 2; ++i)
            #pragma unroll
            for (int r4 = 0; r4 < 4; ++r4) {
                int cl = cbase + i * 16 + l4 * 4 + r4;
                size_t rowb = ((size_t)b * C + cl) * 9216 + r * 96;
                #pragma unroll
                for (int n = 0; n < 6; ++n) {
                    int s = n * 16 + l15;
                    if (OUT16) dstH[rowb + s] = (_Float16)acc[i][n][r4];
                    else       dstF[rowb + s] = acc[i][n][r4];
                }
            }
    }
}

// ---------------------------------------------------------------------------
// fp16 transpose, vectorized (f16x8 granules). Regular loads/stores.
// ---------------------------------------------------------------------------
__global__ __launch_bounds__(256) void transpose_f16(
    const _Float16* __restrict__ src, _Float16* __restrict__ dst)
{
    size_t base = (size_t)blockIdx.x * (96 * 96);
    __shared__ _Float16 t[96][104];
    int tid = threadIdx.x;
    for (int g = tid; g < 1152; g += 256) {
        int row = g / 12, c8 = (g % 12) * 8;
        f16x8 v = *(const f16x8*)&src[base + row * 96 + c8];
        *(f16x8*)&t[row][c8] = v;
    }
    __syncthreads();
    for (int g = tid; g < 1152; g += 256) {
        int row = g / 12, c8 = (g % 12) * 8;
        f16x8 o;
        #pragma unroll
        for (int u = 0; u < 8; ++u) o[u] = t[c8 + u][row];
        *(f16x8*)&dst[base + row * 96 + c8] = o;
    }
}

__global__ __launch_bounds__(256) void transpose_add(
    const _Float16* __restrict__ srcT, float* __restrict__ out)
{
    size_t base = (size_t)blockIdx.x * (96 * 96);
    __shared__ _Float16 t[96][104];
    int tid = threadIdx.x;
    for (int g = tid; g < 1152; g += 256) {
        int row = g / 12, c8 = (g % 12) * 8;
        f16x8 v = *(const f16x8*)&srcT[base + row * 96 + c8];
        *(f16x8*)&t[row][c8] = v;
    }
    __syncthreads();
    for (int i = tid; i < 96 * 96; i += 256) out[base + i] += (float)t[i % 96][i / 96];
}

// out = w16 + transpose(hT), vectorized; nt only on the final out stream.
__global__ __launch_bounds__(256) void combine(
    const _Float16* __restrict__ w16, const _Float16* __restrict__ hT,
    float* __restrict__ out)
{
    size_t base = (size_t)blockIdx.x * (96 * 96);
    __shared__ _Float16 t[96][104];
    int tid = threadIdx.x;
    for (int g = tid; g < 1152; g += 256) {
        int row = g / 12, c8 = (g % 12) * 8;
        f16x8 v = *(const f16x8*)&hT[base + row * 96 + c8];
        *(f16x8*)&t[row][c8] = v;
    }
    __syncthreads();
    for (int g = tid; g < 1152; g += 256) {
        int row = g / 12, c8 = (g % 12) * 8;
        f16x8 wv = *(const f16x8*)&w16[base + row * 96 + c8];
        f32x4 o0, o1;
        #pragma unroll
        for (int u = 0; u < 4; ++u) o0[u] = (float)wv[u] + (float)t[c8 + u][row];
        #pragma unroll
        for (int u = 0; u < 4; ++u) o1[u] = (float)wv[4 + u] + (float)t[c8 + 4 + u][row];
        __builtin_nontemporal_store(o0, (f32x4*)&out[base + row * 96 + c8]);
        __builtin_nontemporal_store(o1, (f32x4*)&out[base + row * 96 + c8 + 4]);
    }
}

// ---------------------------------------------------------------------------
extern "C" void kernel_launch(void* const* d_in, const int* in_sizes, int n_in,
                              void* d_out, int out_size, void* d_ws, size_t ws_size,
                              hipStream_t stream)
{
    const float* x     = (const float*)d_in[0];
    const float* Wq    = (const float*)d_in[1];
    const float* bq    = (const float*)d_in[2];
    const float* Wk    = (const float*)d_in[3];
    const float* bk    = (const float*)d_in[4];
    const float* Wv    = (const float*)d_in[5];
    const float* bv    = (const float*)d_in[6];
    const float* gamma = (const float*)d_in[7];
    float* out = (float*)d_out;

    // Region plan (245.37 MB):
    // R1 75.5MB: xhT -> pW/pH (during energies) -> vB (after combine_ms)
    // R2 75.5MB: xlT -> vA (gemm_v out) -> outHT (after agg_W)
    // R3 37.7MB: q/k hi-lo -> msW/msH (after energies)
    // R4 28.3MB: W splits -> EH16
    // R5 28.3MB: EW16
    const size_t NK = (size_t)B * NSP * KD;
    _Float16* xhT = (_Float16*)d_ws;                         // R1
    _Float16* xlT = xhT + NK;                                // R2
    _Float16* qh  = xlT + NK;                                // R3
    _Float16* ql  = qh + (size_t)B * HW * 64;
    _Float16* kh  = ql + (size_t)B * HW * 64;
    _Float16* kl  = kh + (size_t)B * HW * 64;
    float* R4f = (float*)(kl + (size_t)B * HW * 64);         // R4 base
    float* R5f = R4f + (size_t)B * HW * 96;                  // R5 base
    _Float16* EH16 = (_Float16*)R4f;
    _Float16* EW16 = (_Float16*)R5f;
    float* msW = (float*)qh;                                 // R3 after energies
    float* msH = msW + (size_t)B * HW;
    _Float16* vA  = xlT;                                     // R2 after gemm_v
    _Float16* vB  = xhT;                                     // R1 after combine_ms
    _Float16* outHT = xlT;                                   // R2 after agg_W
    float* pW = (float*)xhT;                                 // R1 during energies
    float* pH = pW + (size_t)2 * B * HW;

    _Float16* Wv_h  = (_Float16*)R4f;                        // R4 until energies
    _Float16* Wqk_h = Wv_h + (size_t)C * C;
    _Float16* Wqk_l = Wqk_h + (size_t)128 * C;

    const size_t NEED = 245366784ull;
    bool bigws = ws_size >= NEED + NK * sizeof(_Float16);
    _Float16* outW16 = (_Float16*)((char*)d_ws + NEED);      // only if bigws

    dim3 blk(256);

    split_w<<<dim3((C*C + 255)/256), blk, 0, stream>>>(Wv, Wq, Wk, Wv_h, Wqk_h, Wqk_l);
    split_x<<<dim3(NSP/64, KD/128, B), blk, 0, stream>>>(x, xhT, xlT);

    // qk first (consumes xlT), then v (overwrites xlT slot with vA)
    gemm_qk<<<dim3(NSP/128, 1, B), blk, 0, stream>>>(xhT, xlT, Wqk_h, Wqk_l, bq, bk, qh, ql, kh, kl);
    gemm_v<<<dim3(NSP/128, C/128, B), blk, 0, stream>>>(xhT, Wv_h, bv, vA);

    // energies (fp16 E-hat) + fused row stats (partials land in dead R1)
    energy_mfma<<<dim3(96, B), blk, 0, stream>>>(qh, ql, kh, kl, EW16, pW, 96, 1);
    energy_mfma<<<dim3(96, B), blk, 0, stream>>>(qh, ql, kh, kl, EH16, pH, 1, 96);
    combine_ms<<<dim3(B*HW/256), blk, 0, stream>>>(pW, pH, gamma, msW, msH);

    // vB = transpose(vA) (overwrites R1 — partials consumed)
    transpose_f16<<<dim3(B*C), blk, 0, stream>>>(vA, vB);

    if (bigws) {
        agg_mfma<1><<<dim3(96, B), blk, 0, stream>>>(EW16, msW, vA, nullptr, outW16, 0);
        agg_mfma<1><<<dim3(96, B), blk, 0, stream>>>(EH16, msH, vB, nullptr, outHT, 1);
        combine<<<dim3(B*C), blk, 0, stream>>>(outW16, outHT, out);
    } else {
        agg_mfma<0><<<dim3(96, B), blk, 0, stream>>>(EW16, msW, vA, out, nullptr, 0);
        agg_mfma<1><<<dim3(96, B), blk, 0, stream>>>(EH16, msH, vB, nullptr, outHT, 1);
        transpose_add<<<dim3(B*C), blk, 0, stream>>>(outHT, out);
    }
}

// Round 12
// 353.598 us; speedup vs baseline: 1.1935x; 1.0069x over previous
//
#include <hip/hip_runtime.h>

#define B 8
#define C 512
#define H 96
#define W 96
#define HW (H*W)       // 9216
#define KD 512
#define NSP 9216

typedef __attribute__((ext_vector_type(4))) float f32x4;
typedef __attribute__((ext_vector_type(8))) _Float16 f16x8;

// global -> LDS async copy, 16B per lane.
typedef __attribute__((address_space(3))) unsigned int lds_u32;
typedef const __attribute__((address_space(1))) unsigned int glb_u32;
static __device__ __forceinline__ void gload16(const void* gsrc, void* ldst) {
    __builtin_amdgcn_global_load_lds((glb_u32*)gsrc, (lds_u32*)ldst, 16, 0, 0);
}

// swizzle for [rows][32-elem] tiles (64B rows, 4 granules of 8) — agg satt only
static __device__ __forceinline__ int tidx(int row, int kgrp) {
    return row * 32 + ((kgrp ^ ((row >> 2) & 3)) << 3);
}
// swizzle for [rows][64-elem] tiles (128B rows, 8 granules) — energy kernel
static __device__ __forceinline__ int tidx64(int row, int gr) {
    return row * 64 + ((gr ^ (row & 7)) << 3);
}

// ---------------------------------------------------------------------------
// Split weights to fp16: Wv single; Wqk = [Wq;Wk] hi/lo pairs.
// ---------------------------------------------------------------------------
__global__ __launch_bounds__(256) void split_w(
    const float* __restrict__ Wv, const float* __restrict__ Wq, const float* __restrict__ Wk,
    _Float16* __restrict__ Wv_h,
    _Float16* __restrict__ Wqk_h, _Float16* __restrict__ Wqk_l)
{
    int i = blockIdx.x * 256 + threadIdx.x;
    if (i < C * C) Wv_h[i] = (_Float16)Wv[i];
    if (i < 128 * C) {
        int m = i / C, k = i % C;
        float f = (m < 64) ? Wq[m * C + k] : Wk[(m - 64) * C + k];
        _Float16 h = (_Float16)f;
        Wqk_h[i] = h;
        Wqk_l[i] = (_Float16)(f - (float)h);
    }
}

// ---------------------------------------------------------------------------
// Global transpose+split of x: (B,K,N) fp32 -> xhT/xlT (B,N,K) fp16.
// Two 64x64 k-tiles per block (8 loads in flight). nt only on x loads
// (true read-once stream); regular stores so consumers hit L2/L3.
// ---------------------------------------------------------------------------
__global__ __launch_bounds__(256) void split_x(
    const float* __restrict__ x,
    _Float16* __restrict__ xhT, _Float16* __restrict__ xlT)
{
    __shared__ float t[2][64][65];      // 33.3 KB
    int n0 = blockIdx.x * 64, k0 = blockIdx.y * 128, b = blockIdx.z;
    int tid = threadIdx.x;
    const float* xb = x + ((size_t)b * KD + k0) * NSP + n0;

    f32x4 v[8];
    #pragma unroll
    for (int it = 0; it < 8; ++it) {
        int idx = tid + it * 256;               // 0..2047
        int tile = idx >> 10, kr = (idx >> 4) & 63, nq = idx & 15;
        v[it] = __builtin_nontemporal_load(
            (const f32x4*)&xb[(size_t)(tile * 64 + kr) * NSP + nq * 4]);
    }
    #pragma unroll
    for (int it = 0; it < 8; ++it) {
        int idx = tid + it * 256;
        int tile = idx >> 10, kr = (idx >> 4) & 63, nq = idx & 15;
        #pragma unroll
        for (int u = 0; u < 4; ++u) t[tile][kr][nq * 4 + u] = v[it][u];
    }
    __syncthreads();
    #pragma unroll
    for (int it = 0; it < 4; ++it) {
        int gid = tid + it * 256;               // 0..1023
        int tile = gid >> 9, w2 = gid & 511;
        int n = w2 >> 3, g = w2 & 7;
        f16x8 hi, lo;
        #pragma unroll
        for (int u = 0; u < 8; ++u) {
            float f = t[tile][g * 8 + u][n];
            _Float16 hh = (_Float16)f;
            hi[u] = hh;
            lo[u] = (_Float16)(f - (float)hh);
        }
        size_t off = ((size_t)b * NSP + n0 + n) * KD + k0 + tile * 64 + g * 8;
        *(f16x8*)&xhT[off] = hi;
        *(f16x8*)&xlT[off] = lo;
    }
}

// ---------------------------------------------------------------------------
// v projection: single-pass fp16 MFMA GEMM (fp32 accum), gload_lds staging.
// Grid: x = m-tile (4), y = n-tile (72) — consecutive blocks share the same
// xhT n-slab for L2 reuse.
// ---------------------------------------------------------------------------
__global__ __launch_bounds__(256, 2) void gemm_v(
    const _Float16* __restrict__ xhT,
    const _Float16* __restrict__ Wh,
    const float* __restrict__ bias,
    _Float16* __restrict__ out16)
{
    __shared__ _Float16 smem[8192];     // [W 128x32 | X 128x32] = 16 KB, linear
    const int W_OFF = 0, X_OFF = 4096;

    int tid = threadIdx.x;
    int m0 = blockIdx.x * 128, n0 = blockIdx.y * 128, b = blockIdx.z;
    int lane = tid & 63, wave = tid >> 6;
    int wr = wave >> 1, wc = wave & 1;
    int l15 = lane & 15, l4 = lane >> 4;

    int grow = tid >> 2, gcol = (tid & 3) * 8;
    const _Float16* pW = Wh + (size_t)(m0 + grow) * KD + gcol;
    const _Float16* pX = xhT + ((size_t)b * NSP + n0 + grow) * KD + gcol;
    const size_t half = (size_t)64 * KD;
    int ldsW0 = W_OFF + wave * 512;
    int ldsW1 = W_OFF + 2048 + wave * 512;
    int ldsX0 = X_OFF + wave * 512;
    int ldsX1 = X_OFF + 2048 + wave * 512;

    f32x4 acc[4][4];
    #pragma unroll
    for (int i = 0; i < 4; ++i)
        #pragma unroll
        for (int j = 0; j < 4; ++j)
            acc[i][j] = (f32x4){0.f, 0.f, 0.f, 0.f};

    for (int k0 = 0; k0 < KD; k0 += 32) {
        gload16(pW + k0,        &smem[ldsW0]);
        gload16(pW + half + k0, &smem[ldsW1]);
        gload16(pX + k0,        &smem[ldsX0]);
        gload16(pX + half + k0, &smem[ldsX1]);
        __syncthreads();

        f16x8 af[4], bf[4];
        #pragma unroll
        for (int f = 0; f < 4; ++f) {
            af[f] = *(const f16x8*)&smem[W_OFF + (wr * 64 + f * 16 + l15) * 32 + l4 * 8];
            bf[f] = *(const f16x8*)&smem[X_OFF + (wc * 64 + f * 16 + l15) * 32 + l4 * 8];
        }
        #pragma unroll
        for (int i = 0; i < 4; ++i)
            #pragma unroll
            for (int j = 0; j < 4; ++j)
                acc[i][j] = __builtin_amdgcn_mfma_f32_16x16x32_f16(af[i], bf[j], acc[i][j], 0, 0, 0);
        __syncthreads();
    }

    #pragma unroll
    for (int i = 0; i < 4; ++i)
        #pragma unroll
        for (int r = 0; r < 4; ++r) {
            int row = m0 + wr * 64 + i * 16 + l4 * 4 + r;
            float bv = bias[row];
            #pragma unroll
            for (int j = 0; j < 4; ++j) {
                int col = n0 + wc * 64 + j * 16 + l15;
                out16[((size_t)b * C + row) * NSP + col] = (_Float16)(acc[i][j][r] + bv);
            }
        }
}

// ---------------------------------------------------------------------------
// q/k projection: 3-pass fp16 (Ah*Bh + Ah*Bl + Al*Bh).
// ---------------------------------------------------------------------------
__global__ __launch_bounds__(256, 2) void gemm_qk(
    const _Float16* __restrict__ xhT, const _Float16* __restrict__ xlT,
    const _Float16* __restrict__ Wqh, const _Float16* __restrict__ Wql,
    const float* __restrict__ bias0, const float* __restrict__ bias1,
    _Float16* __restrict__ qh, _Float16* __restrict__ ql,
    _Float16* __restrict__ kh, _Float16* __restrict__ kl)
{
    __shared__ _Float16 smem[16384];    // [XH|XL|WH|WL] each 128x32 = 32 KB
    const int XH = 0, XL = 4096, WHo = 8192, WLo = 12288;

    int tid = threadIdx.x;
    int n0 = blockIdx.x * 128, b = blockIdx.z;
    int lane = tid & 63, wave = tid >> 6;
    int wr = wave >> 1, wc = wave & 1;
    int l15 = lane & 15, l4 = lane >> 4;

    int grow = tid >> 2, gcol = (tid & 3) * 8;
    const _Float16* pXh = xhT + ((size_t)b * NSP + n0 + grow) * KD + gcol;
    const _Float16* pXl = xlT + ((size_t)b * NSP + n0 + grow) * KD + gcol;
    const _Float16* pWh = Wqh + (size_t)grow * KD + gcol;
    const _Float16* pWl = Wql + (size_t)grow * KD + gcol;
    const size_t half = (size_t)64 * KD;
    int base0 = wave * 512, base1 = 2048 + wave * 512;

    f32x4 acc[4][4];
    #pragma unroll
    for (int i = 0; i < 4; ++i)
        #pragma unroll
        for (int j = 0; j < 4; ++j)
            acc[i][j] = (f32x4){0.f, 0.f, 0.f, 0.f};

    for (int k0 = 0; k0 < KD; k0 += 32) {
        gload16(pXh + k0,        &smem[XH + base0]);
        gload16(pXh + half + k0, &smem[XH + base1]);
        gload16(pXl + k0,        &smem[XL + base0]);
        gload16(pXl + half + k0, &smem[XL + base1]);
        gload16(pWh + k0,        &smem[WHo + base0]);
        gload16(pWh + half + k0, &smem[WHo + base1]);
        gload16(pWl + k0,        &smem[WLo + base0]);
        gload16(pWl + half + k0, &smem[WLo + base1]);
        __syncthreads();

        f16x8 axh[4], axl[4], bwh[4], bwl[4];
        #pragma unroll
        for (int f = 0; f < 4; ++f) {
            int ra = (wr * 64 + f * 16 + l15) * 32 + l4 * 8;
            int rb = (wc * 64 + f * 16 + l15) * 32 + l4 * 8;
            axh[f] = *(const f16x8*)&smem[XH + ra];
            axl[f] = *(const f16x8*)&smem[XL + ra];
            bwh[f] = *(const f16x8*)&smem[WHo + rb];
            bwl[f] = *(const f16x8*)&smem[WLo + rb];
        }
        #pragma unroll
        for (int i = 0; i < 4; ++i)
            #pragma unroll
            for (int j = 0; j < 4; ++j)
                acc[i][j] = __builtin_amdgcn_mfma_f32_16x16x32_f16(axh[i], bwh[j], acc[i][j], 0, 0, 0);
        #pragma unroll
        for (int i = 0; i < 4; ++i)
            #pragma unroll
            for (int j = 0; j < 4; ++j)
                acc[i][j] = __builtin_amdgcn_mfma_f32_16x16x32_f16(axh[i], bwl[j], acc[i][j], 0, 0, 0);
        #pragma unroll
        for (int i = 0; i < 4; ++i)
            #pragma unroll
            for (int j = 0; j < 4; ++j)
                acc[i][j] = __builtin_amdgcn_mfma_f32_16x16x32_f16(axl[i], bwh[j], acc[i][j], 0, 0, 0);
        __syncthreads();
    }

    #pragma unroll
    for (int i = 0; i < 4; ++i)
        #pragma unroll
        for (int r = 0; r < 4; ++r) {
            int sp = n0 + wr * 64 + i * 16 + l4 * 4 + r;
            #pragma unroll
            for (int j = 0; j < 4; ++j) {
                int wcol = wc * 64 + j * 16 + l15;
                float val = acc[i][j][r] + (wcol < 64 ? bias0[wcol] : bias1[wcol - 64]);
                _Float16 hi = (_Float16)val;
                _Float16 lo = (_Float16)(val - (float)hi);
                size_t off = ((size_t)b * NSP + sp) * 64 + (wcol & 63);
                if (wcol < 64) { qh[off] = hi; ql[off] = lo; }
                else           { kh[off] = hi; kl[off] = lo; }
            }
        }
}

// ---------------------------------------------------------------------------
// Energy MFMA: 3-pass fp16 + fused per-row (max, sum-exp) stats.
// Writes E-hat = E - rowmax(direction) as FP16 (halves E traffic).
// ---------------------------------------------------------------------------
__global__ __launch_bounds__(256, 2) void energy_mfma(
    const _Float16* __restrict__ qh, const _Float16* __restrict__ ql,
    const _Float16* __restrict__ kh, const _Float16* __restrict__ kl,
    _Float16* __restrict__ out16, float* __restrict__ part, int pMul, int rMul)
{
    __shared__ _Float16 sm[4 * 96 * 64];   // 48 KB
    const int T_QH = 0, T_QL = 6144, T_KH = 12288, T_KL = 18432;
    int p = blockIdx.x, b = blockIdx.y;
    int tid = threadIdx.x;
    size_t base = ((size_t)b * HW + (size_t)p * pMul) * 64;
    size_t rstride = (size_t)rMul * 64;

    #pragma unroll
    for (int tile = 0; tile < 4; ++tile) {
        const _Float16* src = (tile == 0) ? qh : (tile == 1) ? ql : (tile == 2) ? kh : kl;
        int tb = tile * 6144;
        #pragma unroll
        for (int sub = 0; sub < 3; ++sub) {
            int s = sub * 256 + tid;
            int row = s >> 3, g = s & 7;
            f16x8 d = *(const f16x8*)&src[base + row * rstride + g * 8];
            *(f16x8*)&sm[tb + tidx64(row, g)] = d;
        }
    }
    __syncthreads();

    int lane = tid & 63, wave = tid >> 6;
    int wr = wave >> 1, wc = wave & 1;
    int l15 = lane & 15, l4 = lane >> 4;

    f32x4 acc[3][3];
    #pragma unroll
    for (int i = 0; i < 3; ++i)
        #pragma unroll
        for (int j = 0; j < 3; ++j)
            acc[i][j] = (f32x4){0.f, 0.f, 0.f, 0.f};

    #pragma unroll
    for (int ks = 0; ks < 2; ++ks) {
        f16x8 Ah[3], Al[3], Bh[3], Bl[3];
        int gr = ks * 4 + l4;
        #pragma unroll
        for (int i = 0; i < 3; ++i) {
            int sa = tidx64(wr * 48 + i * 16 + l15, gr);
            Ah[i] = *(const f16x8*)&sm[T_QH + sa];
            Al[i] = *(const f16x8*)&sm[T_QL + sa];
            int sb = tidx64(wc * 48 + i * 16 + l15, gr);
            Bh[i] = *(const f16x8*)&sm[T_KH + sb];
            Bl[i] = *(const f16x8*)&sm[T_KL + sb];
        }
        #pragma unroll
        for (int i = 0; i < 3; ++i)
            #pragma unroll
            for (int j = 0; j < 3; ++j) {
                acc[i][j] = __builtin_amdgcn_mfma_f32_16x16x32_f16(Ah[i], Bh[j], acc[i][j], 0, 0, 0);
                acc[i][j] = __builtin_amdgcn_mfma_f32_16x16x32_f16(Ah[i], Bl[j], acc[i][j], 0, 0, 0);
                acc[i][j] = __builtin_amdgcn_mfma_f32_16x16x32_f16(Al[i], Bh[j], acc[i][j], 0, 0, 0);
            }
    }

    // ---- per-row stats (exact: block owns the full 96-col row) ----
    __syncthreads();                    // fragment ds_reads done -> reuse sm
    float* scr  = (float*)sm;           // [96][4]: mW0,s0,m1,s1
    float* scrM = scr + 384;            // [96]: full row max
    #pragma unroll
    for (int i = 0; i < 3; ++i)
        #pragma unroll
        for (int r = 0; r < 4; ++r) {
            int row = wr * 48 + i * 16 + l4 * 4 + r;
            float m3 = fmaxf(fmaxf(acc[i][0][r], acc[i][1][r]), acc[i][2][r]);
            #pragma unroll
            for (int mk = 1; mk < 16; mk <<= 1) m3 = fmaxf(m3, __shfl_xor(m3, mk));
            float s = __expf(acc[i][0][r] - m3) + __expf(acc[i][1][r] - m3) + __expf(acc[i][2][r] - m3);
            #pragma unroll
            for (int mk = 1; mk < 16; mk <<= 1) s += __shfl_xor(s, mk);
            if (l15 == 0) {
                scr[row * 4 + wc * 2]     = m3;
                scr[row * 4 + wc * 2 + 1] = s;
            }
        }
    __syncthreads();
    if (tid < 96) {
        float m0 = scr[tid * 4], s0 = scr[tid * 4 + 1];
        float m1 = scr[tid * 4 + 2], s1 = scr[tid * 4 + 3];
        float M = fmaxf(m0, m1);
        float S = s0 * __expf(m0 - M) + s1 * __expf(m1 - M);
        size_t idx = (pMul == 96) ? ((size_t)b * HW + p * 96 + tid)
                                  : ((size_t)b * HW + tid * 96 + p);
        part[idx * 2]     = M;
        part[idx * 2 + 1] = S;
        scrM[tid] = M;
    }
    __syncthreads();

    // ---- write E-hat = E - rowmax as fp16 ----
    size_t ob = (size_t)(b * 96 + p) * 9216;
    #pragma unroll
    for (int i = 0; i < 3; ++i)
        #pragma unroll
        for (int r = 0; r < 4; ++r) {
            int row = wr * 48 + i * 16 + l4 * 4 + r;
            float Mrow = scrM[row];
            #pragma unroll
            for (int j = 0; j < 3; ++j)
                out16[ob + (size_t)row * 96 + wc * 48 + j * 16 + l15] =
                    (_Float16)(acc[i][j][r] - Mrow);
        }
}

// ---------------------------------------------------------------------------
// Combine W/H stats -> per-direction scales: msX = gamma*exp(mX-M)/S_total.
// ---------------------------------------------------------------------------
__global__ __launch_bounds__(256) void combine_ms(
    const float* __restrict__ pW, const float* __restrict__ pH,
    const float* __restrict__ gamma,
    float* __restrict__ msW, float* __restrict__ msH)
{
    int row = blockIdx.x * 256 + threadIdx.x;
    float mW = pW[row * 2], sW = pW[row * 2 + 1];
    float mH = pH[row * 2], sH = pH[row * 2 + 1];
    float M = fmaxf(mW, mH);
    float eW = __expf(mW - M), eH = __expf(mH - M);
    float g = gamma[0] / (sW * eW + sH * eH);
    msW[row] = g * eW;
    msH[row] = g * eH;
}

// ---------------------------------------------------------------------------
// MFMA aggregation: P staged once (from fp16 E-hat), v direct-from-global.
// ---------------------------------------------------------------------------
template<int OUT16>
__global__ __launch_bounds__(256, 2) void agg_mfma(
    const _Float16* __restrict__ E16, const float* __restrict__ msDir,
    const _Float16* __restrict__ v16,
    float* __restrict__ dstF, _Float16* __restrict__ dstH, int msMode)
{
    __shared__ _Float16 satt[3][96 * 32];   // 18 KB

    int r = blockIdx.x, b = blockIdx.y;
    int tid = threadIdx.x;
    int lane = tid & 63, wave = tid >> 6;
    int l15 = lane & 15, l4 = lane >> 4;

    const _Float16* Eb = &E16[(size_t)(b * 96 + r) * 9216];
    int msBase = b * HW;
    #pragma unroll
    for (int it = 0; it < 5; ++it) {
        int g_id = tid + it * 256;
        if (g_id < 1152) {
            int s = g_id / 12, gj = g_id % 12;
            int mi = msMode ? (msBase + s * 96 + r) : (msBase + r * 96 + s);
            float sc = msDir[mi];
            f16x8 ev = *(const f16x8*)&Eb[s * 96 + gj * 8];
            f16x8 ph;
            #pragma unroll
            for (int u = 0; u < 8; ++u)
                ph[u] = (_Float16)(__expf((float)ev[u]) * sc);
            *(f16x8*)&satt[gj >> 2][tidx(s, gj & 3)] = ph;
        }
    }
    __syncthreads();

    const _Float16* vb = v16 + (size_t)b * C * 9216 + r * 96;

    #pragma unroll
    for (int cc = 0; cc < 4; ++cc) {
        int cbase = cc * 128 + wave * 32;
        f32x4 acc[2][6];
        #pragma unroll
        for (int i = 0; i < 2; ++i)
            #pragma unroll
            for (int n = 0; n < 6; ++n)
                acc[i][n] = (f32x4){0.f, 0.f, 0.f, 0.f};

        #pragma unroll
        for (int kc = 0; kc < 3; ++kc) {
            f16x8 af[2];
            #pragma unroll
            for (int i = 0; i < 2; ++i)
                af[i] = *(const f16x8*)&vb[(size_t)(cbase + i * 16 + l15) * 9216 + kc * 32 + l4 * 8];
            f16x8 Bp[6];
            #pragma unroll
            for (int n = 0; n < 6; ++n)
                Bp[n] = *(const f16x8*)&satt[kc][tidx(n * 16 + l15, l4)];
            #pragma unroll
            for (int i = 0; i < 2; ++i)
                #pragma unroll
                for (int n = 0; n < 6; ++n)
                    acc[i][n] = __builtin_amdgcn_mfma_f32_16x16x32_f16(af[i], Bp[n], acc[i][n], 0, 0, 0);
        }

        #pragma unroll
        for (int i = 0; i < 2; ++i)
            #pragma unroll
            for (int r4 = 0; r4 < 4; ++r4) {
                int cl = cbase + i * 16 + l4 * 4 + r4;
                size_t rowb = ((size_t)b * C + cl) * 9216 + r * 96;
                #pragma unroll
                for (int n = 0; n < 6; ++n) {
                    int s = n * 16 + l15;
                    if (OUT16) dstH[rowb + s] = (_Float16)acc[i][n][r4];
                    else       dstF[rowb + s] = acc[i][n][r4];
                }
            }
    }
}

// ---------------------------------------------------------------------------
// fp16 transpose, vectorized (f16x8 granules).
// ---------------------------------------------------------------------------
__global__ __launch_bounds__(256) void transpose_f16(
    const _Float16* __restrict__ src, _Float16* __restrict__ dst)
{
    size_t base = (size_t)blockIdx.x * (96 * 96);
    __shared__ _Float16 t[96][104];
    int tid = threadIdx.x;
    for (int g = tid; g < 1152; g += 256) {
        int row = g / 12, c8 = (g % 12) * 8;
        f16x8 v = *(const f16x8*)&src[base + row * 96 + c8];
        *(f16x8*)&t[row][c8] = v;
    }
    __syncthreads();
    for (int g = tid; g < 1152; g += 256) {
        int row = g / 12, c8 = (g % 12) * 8;
        f16x8 o;
        #pragma unroll
        for (int u = 0; u < 8; ++u) o[u] = t[c8 + u][row];
        *(f16x8*)&dst[base + row * 96 + c8] = o;
    }
}

__global__ __launch_bounds__(256) void transpose_add(
    const _Float16* __restrict__ srcT, float* __restrict__ out)
{
    size_t base = (size_t)blockIdx.x * (96 * 96);
    __shared__ _Float16 t[96][104];
    int tid = threadIdx.x;
    for (int g = tid; g < 1152; g += 256) {
        int row = g / 12, c8 = (g % 12) * 8;
        f16x8 v = *(const f16x8*)&srcT[base + row * 96 + c8];
        *(f16x8*)&t[row][c8] = v;
    }
    __syncthreads();
    for (int i = tid; i < 96 * 96; i += 256) out[base + i] += (float)t[i % 96][i / 96];
}

// out = w16 + transpose(hT), vectorized; nt only on the final out stream.
__global__ __launch_bounds__(256) void combine(
    const _Float16* __restrict__ w16, const _Float16* __restrict__ hT,
    float* __restrict__ out)
{
    size_t base = (size_t)blockIdx.x * (96 * 96);
    __shared__ _Float16 t[96][104];
    int tid = threadIdx.x;
    for (int g = tid; g < 1152; g += 256) {
        int row = g / 12, c8 = (g % 12) * 8;
        f16x8 v = *(const f16x8*)&hT[base + row * 96 + c8];
        *(f16x8*)&t[row][c8] = v;
    }
    __syncthreads();
    for (int g = tid; g < 1152; g += 256) {
        int row = g / 12, c8 = (g % 12) * 8;
        f16x8 wv = *(const f16x8*)&w16[base + row * 96 + c8];
        f32x4 o0, o1;
        #pragma unroll
        for (int u = 0; u < 4; ++u) o0[u] = (float)wv[u] + (float)t[c8 + u][row];
        #pragma unroll
        for (int u = 0; u < 4; ++u) o1[u] = (float)wv[4 + u] + (float)t[c8 + 4 + u][row];
        __builtin_nontemporal_store(o0, (f32x4*)&out[base + row * 96 + c8]);
        __builtin_nontemporal_store(o1, (f32x4*)&out[base + row * 96 + c8 + 4]);
    }
}

// ---------------------------------------------------------------------------
extern "C" void kernel_launch(void* const* d_in, const int* in_sizes, int n_in,
                              void* d_out, int out_size, void* d_ws, size_t ws_size,
                              hipStream_t stream)
{
    const float* x     = (const float*)d_in[0];
    const float* Wq    = (const float*)d_in[1];
    const float* bq    = (const float*)d_in[2];
    const float* Wk    = (const float*)d_in[3];
    const float* bk    = (const float*)d_in[4];
    const float* Wv    = (const float*)d_in[5];
    const float* bv    = (const float*)d_in[6];
    const float* gamma = (const float*)d_in[7];
    float* out = (float*)d_out;

    // Region plan (245.37 MB):
    // R1 75.5MB: xhT -> pW/pH (during energies) -> vB (after combine_ms)
    // R2 75.5MB: xlT -> vA (gemm_v out) -> outHT (after agg_W)
    // R3 37.7MB: q/k hi-lo -> msW/msH (after energies)
    // R4 28.3MB: W splits -> EH16
    // R5 28.3MB: EW16
    const size_t NK = (size_t)B * NSP * KD;
    _Float16* xhT = (_Float16*)d_ws;                         // R1
    _Float16* xlT = xhT + NK;                                // R2
    _Float16* qh  = xlT + NK;                                // R3
    _Float16* ql  = qh + (size_t)B * HW * 64;
    _Float16* kh  = ql + (size_t)B * HW * 64;
    _Float16* kl  = kh + (size_t)B * HW * 64;
    float* R4f = (float*)(kl + (size_t)B * HW * 64);         // R4 base
    float* R5f = R4f + (size_t)B * HW * 96;                  // R5 base
    _Float16* EH16 = (_Float16*)R4f;
    _Float16* EW16 = (_Float16*)R5f;
    float* msW = (float*)qh;                                 // R3 after energies
    float* msH = msW + (size_t)B * HW;
    _Float16* vA  = xlT;                                     // R2 after gemm_v
    _Float16* vB  = xhT;                                     // R1 after combine_ms
    _Float16* outHT = xlT;                                   // R2 after agg_W
    float* pW = (float*)xhT;                                 // R1 during energies
    float* pH = pW + (size_t)2 * B * HW;

    _Float16* Wv_h  = (_Float16*)R4f;                        // R4 until energies
    _Float16* Wqk_h = Wv_h + (size_t)C * C;
    _Float16* Wqk_l = Wqk_h + (size_t)128 * C;

    const size_t NEED = 245366784ull;
    bool bigws = ws_size >= NEED + NK * sizeof(_Float16);
    _Float16* outW16 = (_Float16*)((char*)d_ws + NEED);      // only if bigws

    dim3 blk(256);

    split_w<<<dim3((C*C + 255)/256), blk, 0, stream>>>(Wv, Wq, Wk, Wv_h, Wqk_h, Wqk_l);
    split_x<<<dim3(NSP/64, KD/128, B), blk, 0, stream>>>(x, xhT, xlT);

    // qk first (consumes xlT), then v (overwrites xlT slot with vA)
    gemm_qk<<<dim3(NSP/128, 1, B), blk, 0, stream>>>(xhT, xlT, Wqk_h, Wqk_l, bq, bk, qh, ql, kh, kl);
    gemm_v<<<dim3(C/128, NSP/128, B), blk, 0, stream>>>(xhT, Wv_h, bv, vA);

    // energies (fp16 E-hat) + fused row stats (partials land in dead R1)
    energy_mfma<<<dim3(96, B), blk, 0, stream>>>(qh, ql, kh, kl, EW16, pW, 96, 1);
    energy_mfma<<<dim3(96, B), blk, 0, stream>>>(qh, ql, kh, kl, EH16, pH, 1, 96);
    combine_ms<<<dim3(B*HW/256), blk, 0, stream>>>(pW, pH, gamma, msW, msH);

    // vB = transpose(vA) (overwrites R1 — partials consumed)
    transpose_f16<<<dim3(B*C), blk, 0, stream>>>(vA, vB);

    if (bigws) {
        agg_mfma<1><<<dim3(96, B), blk, 0, stream>>>(EW16, msW, vA, nullptr, outW16, 0);
        agg_mfma<1><<<dim3(96, B), blk, 0, stream>>>(EH16, msH, vB, nullptr, outHT, 1);
        combine<<<dim3(B*C), blk, 0, stream>>>(outW16, outHT, out);
    } else {
        agg_mfma<0><<<dim3(96, B), blk, 0, stream>>>(EW16, msW, vA, out, nullptr, 0);
        agg_mfma<1><<<dim3(96, B), blk, 0, stream>>>(EH16, msH, vB, nullptr, outHT, 1);
        transpose_add<<<dim3(B*C), blk, 0, stream>>>(outHT, out);
    }
}